// Round 13
// baseline (607.184 us; speedup 1.0000x reference)
//
#include <hip/hip_runtime.h>
#include <hip/hip_bf16.h>

#define NN 2000   // nodes
#define NP 2048   // padded
#define BB 8
#define HH 64
#define DD 16

typedef __hip_bfloat16 bf16;
typedef short bf16x8 __attribute__((ext_vector_type(8)));  // 8 bf16 in 4 VGPRs
typedef float f32x4 __attribute__((ext_vector_type(4)));

__device__ __forceinline__ float fast_sigmoid(float x) {
    return 1.0f / (1.0f + __expf(-x));
}
__device__ __forceinline__ float fast_tanh(float x) {
    float e = __expf(2.0f * x);           // inf-safe: x>>0 -> 1, x<<0 -> -1
    return 1.0f - 2.0f / (e + 1.0f);
}

// async 16B global->LDS. LDS dest = wave-uniform base + lane*16 (m97/m104).
__device__ __forceinline__ void glds16(const void* g, void* l) {
    __builtin_amdgcn_global_load_lds(
        (const __attribute__((address_space(1))) void*)g,
        (__attribute__((address_space(3))) void*)l, 16, 0, 0);
}

// ---------------------------------------------------------------------------
// h = relu(z @ W_in^T + b_in); e1 = h@w1, e2 = h@w2.
// 8 rows per block (W_in staging amortized 8x). Per-row math bit-identical.
// ---------------------------------------------------------------------------
__global__ __launch_bounds__(256) void k_h(
        const float* __restrict__ z, const float* __restrict__ W_in,
        const float* __restrict__ b_in, const float* __restrict__ w1,
        const float* __restrict__ w2, float* __restrict__ h,
        float* __restrict__ e1, float* __restrict__ e2) {
    __shared__ float WT[64 * 65];
    __shared__ float zs[8][64];
    int t = threadIdx.x;
    int lane = t & 63, ty = t >> 6;
    int bn0 = blockIdx.x * 8;
    for (int i = t; i < 64 * 64; i += 256) {
        int hh = i >> 6, c = i & 63;
        WT[c * 65 + hh] = W_in[i];           // WT[c][h] = W_in[h][c]
    }
    #pragma unroll
    for (int q = 0; q < 2; q++) {
        int r = ty * 2 + q;
        zs[r][lane] = z[(size_t)(bn0 + r) * 64 + lane];
    }
    __syncthreads();
    #pragma unroll
    for (int q = 0; q < 2; q++) {
        int r = ty * 2 + q;
        float acc = b_in[lane];
        #pragma unroll
        for (int c = 0; c < 64; c++) acc += zs[r][c] * WT[c * 65 + lane];
        float hv = fmaxf(acc, 0.0f);
        h[(size_t)(bn0 + r) * 64 + lane] = hv;
        float p1 = hv * w1[lane], p2 = hv * w2[lane];
        #pragma unroll
        for (int off = 32; off > 0; off >>= 1) {
            p1 += __shfl_down(p1, off);
            p2 += __shfl_down(p2, off);
        }
        if (lane == 0) { e1[bn0 + r] = p1; e2[bn0 + r] = p2; }
    }
}

// ---------------------------------------------------------------------------
// MEGA kernel: one launch for all mid-size independent work (R11, unchanged).
// ---------------------------------------------------------------------------
__global__ __launch_bounds__(256) void k_mega(
        const float* __restrict__ e1, const float* __restrict__ e2,
        const float* __restrict__ bs, bf16* __restrict__ Tt,
        const float* __restrict__ vs, bf16* __restrict__ vs_bf,
        const float* __restrict__ emb, bf16* __restrict__ A,
        const float* __restrict__ wp, float* __restrict__ Wn_all,
        const float* __restrict__ h, bf16* __restrict__ hTcat,
        bf16* __restrict__ hsT,
        const float* __restrict__ W_out, bf16* __restrict__ Wo_bf) {
    __shared__ float smem[4160];
    int bid = blockIdx.x, t = threadIdx.x;

    if (bid < 1024) {                    // ---- k_Tt, all 8 batches per tile
        int mt = bid & 31, pt = bid >> 5;
        float* tile = smem;              // tile[i_m*65 + tx_p] = bs[m0+i][p0+tx]
        int tx = t & 63, ty = t >> 6;
        int m0 = mt * 64, p0 = pt * 64;
        for (int i = ty * 16; i < ty * 16 + 16; i++) {
            int m = m0 + i, p = p0 + tx;
            tile[i * 65 + tx] = (m < NN && p < NN) ? bs[(size_t)m * NN + p] : 0.0f;
        }
        __syncthreads();                 // tile read-only from here: no more syncs
        int m = m0 + tx;
        for (int b = 0; b < BB; b++) {
            float e1v = (m < NN) ? e1[b * NN + m] : 0.0f;
            bf16* Tb = Tt + (size_t)b * NP * NP;
            for (int i = ty * 16; i < ty * 16 + 16; i++) {
                int p = p0 + i;
                float v = 0.0f;
                if (m < NN && p < NN)
                    v = fast_sigmoid(e1v * e2[b * NN + p] + tile[tx * 65 + i]);
                Tb[((size_t)p) * NP + m] = __float2bfloat16(v);
            }
        }
        return;
    }
    bid -= 1024;
    if (bid < 16384) {                   // ---- cvt_vs
        int id = bid * 256 + t;
        int n = id >> 11, m = id & (NP - 1);
        float v = (n < NN && m < NN) ? vs[n * NN + m] : 0.0f;
        vs_bf[id] = __float2bfloat16(v);
        return;
    }
    bid -= 16384;
    if (bid < 2048) {                    // ---- k_A
        int i = bid;
        if (i >= NN) {
            for (int j = t; j < NP; j += 256) A[(size_t)i * NP + j] = __float2bfloat16(0.0f);
            return;
        }
        float* rowbuf = smem;            // 2048
        float* red = smem + 2048;        // 256
        float* ei = smem + 2304;         // 16
        if (t < DD) ei[t] = emb[i * DD + t];
        __syncthreads();
        float lmax = -1e30f;
        for (int j = t; j < NP; j += 256) {
            float s = 0.0f;
            if (j < NN) {
                #pragma unroll
                for (int d = 0; d < DD; d++) s += ei[d] * emb[j * DD + d];
                s = fmaxf(s, 0.0f);
                lmax = fmaxf(lmax, s);
            }
            rowbuf[j] = s;
        }
        red[t] = lmax; __syncthreads();
        for (int o = 128; o > 0; o >>= 1) { if (t < o) red[t] = fmaxf(red[t], red[t + o]); __syncthreads(); }
        float mx = red[0];
        __syncthreads();
        float lsum = 0.0f;
        for (int j = t; j < NN; j += 256) {
            float e = __expf(rowbuf[j] - mx);
            rowbuf[j] = e; lsum += e;
        }
        red[t] = lsum; __syncthreads();
        for (int o = 128; o > 0; o >>= 1) { if (t < o) red[t] += red[t + o]; __syncthreads(); }
        float inv = 1.0f / red[0];
        for (int j = t; j < NP; j += 256)
            A[(size_t)i * NP + j] = __float2bfloat16(j < NN ? rowbuf[j] * inv : 0.0f);
        return;
    }
    bid -= 2048;
    if (bid < 512) {                     // ---- k_wn
        float* embs = smem;              // 2048
        int n0 = (bid & 15) * 128;
        int jo = (bid >> 4) * 256 + t;   // j*64+o, < 8192
        float wv[16];
        #pragma unroll
        for (int d = 0; d < 16; d++) wv[d] = wp[(size_t)d * 8192 + jo];
        for (int s = t; s < 128 * 16; s += 256) {
            int i = s >> 4, d = s & 15;
            int n = n0 + i;
            embs[s] = (n < NN) ? emb[n * 16 + d] : 0.f;
        }
        __syncthreads();
        for (int i = 0; i < 128; i++) {
            int n = n0 + i;
            if (n >= NN) break;
            const f32x4* ev = (const f32x4*)&embs[i * 16];
            f32x4 ea = ev[0], eb = ev[1], ec = ev[2], ed = ev[3];
            float a = 0.f;
            #pragma unroll
            for (int q = 0; q < 4; q++) a += ea[q] * wv[q];
            #pragma unroll
            for (int q = 0; q < 4; q++) a += eb[q] * wv[4 + q];
            #pragma unroll
            for (int q = 0; q < 4; q++) a += ec[q] * wv[8 + q];
            #pragma unroll
            for (int q = 0; q < 4; q++) a += ed[q] * wv[12 + q];
            Wn_all[(size_t)n * 8192 + jo] = a;
        }
        return;
    }
    bid -= 512;
    if (bid < 256) {                     // ---- k_hT
        float* tile = smem;
        int nt = bid & 31, b = bid >> 5;
        int tx = t & 63, ty = t >> 6;
        int n0 = nt * 64;
        for (int i = ty * 16; i < ty * 16 + 16; i++) {
            int n = n0 + i;
            tile[i * 65 + tx] = (n < NN) ? h[((size_t)b * NN + n) * 64 + tx] : 0.0f;
        }
        __syncthreads();
        for (int i = ty * 16; i < ty * 16 + 16; i++) {
            bf16 v = __float2bfloat16(tile[tx * 65 + i]);   // h[b][n0+tx][i]
            hTcat[((size_t)b * 64 + i) * NP + n0 + tx] = v;
            hsT[((size_t)b * 128 + i) * NP + n0 + tx] = v;
        }
        return;
    }
    bid -= 256;
    {                                    // ---- cvt_wout (1024 blocks)
        int id = bid * 256 + t;          // 4096*64
        Wo_bf[id] = __float2bfloat16(W_out[id]);
    }
}

// ---------------------------------------------------------------------------
// merged reduce4 + transpose: hsT[b*128+64+c][p] = sum_sl AhPart[sl][p][b*64+c]
// ---------------------------------------------------------------------------
__global__ __launch_bounds__(256) void k_redT(const float* __restrict__ AhPart,
                                              bf16* __restrict__ hsT) {
    __shared__ float tile[64 * 65];
    int pt = blockIdx.x, b = blockIdx.y;
    int tx = threadIdx.x & 63, ty = threadIdx.x >> 6;
    int p0 = pt * 64, q0 = b * 64;
    const long long TOT = (long long)NP * 512;
    for (int i = ty * 16; i < ty * 16 + 16; i++) {
        long long base = ((long long)p0 + i) * 512 + q0 + tx;
        float s = AhPart[base];
        #pragma unroll
        for (int sl = 1; sl < 4; sl++) s += AhPart[sl * TOT + base];
        tile[i * 65 + tx] = s;
    }
    __syncthreads();
    for (int i = ty * 16; i < ty * 16 + 16; i++)
        hsT[((size_t)b * 128 + 64 + i) * NP + p0 + tx] =
            __float2bfloat16(tile[tx * 65 + i]);
}

// ---------------------------------------------------------------------------
// 256x256-tile bf16 MFMA GEMM, 8-phase region-partitioned pipeline (R10)
// + XCD swizzle (R12) + NEW: 1-phase A-FRAGMENT PREFETCH.
// Timeline proof: region read at phases (p+2,p+3) has A-half staged at p-4,
// covered by the vmcnt(8) at end of phase p -> a[8] reads may issue during
// phase p+1, overlapping its MFMA. B-half (staged p-3) is covered only at
// end of p+1 -> b reads stay in-phase but issue BEFORE the MFMA with counted
// lgkmcnt: phase A {issue b0..b3; lgkmcnt(2) waits prev aC+b01; MFMA | b23
// lands}, phase B {issue next aN[8]; lgkmcnt(8) waits b23; MFMA | aN lands}.
// Exposed LDS latency/pair ~300cy -> ~100cy. aA/aB parity-static (rule #20).
// Final iteration: safe lgkmcnt(0) form (tail vmcnt too tight for prefetch).
// Accumulation order unchanged -> bit-identical output.
// ---------------------------------------------------------------------------
#define MFMA_B16 __builtin_amdgcn_mfma_f32_16x16x32_bf16
#define VM8 asm volatile("s_waitcnt vmcnt(8)" ::: "memory")
#define VM4 asm volatile("s_waitcnt vmcnt(4)" ::: "memory")
#define VM0 asm volatile("s_waitcnt vmcnt(0)" ::: "memory")
#define VMN
#define SBAR __builtin_amdgcn_s_barrier()
#define SCB  __builtin_amdgcn_sched_barrier(0)
#define LDB(BUF, KH, J) \
    (*(const bf16x8*)(LDSb + 32768 + (BUF) * 16384 + (KH) * 8192 + boff[J]))

// steady-state pair: phases (BUF,KH,jp0) and (BUF,KH,jp1); prefetches the
// NEXT pair's a-fragments (region NB,NK) during phase B.
#define SPAIR(BUF, KH, NB, NK, AC, AN, S1, S2, V1, V2)                       \
  {                                                                          \
    bq[0] = LDB(BUF, KH, 0); bq[1] = LDB(BUF, KH, 1);                        \
    bq[2] = LDB(BUF, KH, 2); bq[3] = LDB(BUF, KH, 3);                        \
    S1;                                                                      \
    asm volatile("s_waitcnt lgkmcnt(2)" ::: "memory");                       \
    SCB;                                                                     \
    __builtin_amdgcn_s_setprio(1);                                           \
    _Pragma("unroll")                                                        \
    for (int ii = 0; ii < 8; ii++) {                                         \
      acc[ii][0] = MFMA_B16(AC[ii], bq[0], acc[ii][0], 0, 0, 0);             \
      acc[ii][1] = MFMA_B16(AC[ii], bq[1], acc[ii][1], 0, 0, 0);             \
    }                                                                        \
    __builtin_amdgcn_s_setprio(0);                                           \
    SCB; V1; SBAR; SCB;                                                      \
    _Pragma("unroll")                                                        \
    for (int ii = 0; ii < 8; ii++)                                           \
      AN[ii] = *(const bf16x8*)(LDSb + (NB) * 16384 + (NK) * 8192 + aoff[ii]); \
    S2;                                                                      \
    asm volatile("s_waitcnt lgkmcnt(8)" ::: "memory");                       \
    SCB;                                                                     \
    __builtin_amdgcn_s_setprio(1);                                           \
    _Pragma("unroll")                                                        \
    for (int ii = 0; ii < 8; ii++) {                                         \
      acc[ii][2] = MFMA_B16(AC[ii], bq[2], acc[ii][2], 0, 0, 0);             \
      acc[ii][3] = MFMA_B16(AC[ii], bq[3], acc[ii][3], 0, 0, 0);             \
    }                                                                        \
    __builtin_amdgcn_s_setprio(0);                                           \
    SCB; V2; SBAR; SCB;                                                      \
  }

// final-iteration phase: conservative lgkmcnt(0), optional a re-read.
#define FPHASE(BUF, KH, JP, READA, STAGE, VMS)                               \
  {                                                                          \
    if (READA) {                                                             \
      _Pragma("unroll")                                                      \
      for (int ii = 0; ii < 8; ii++)                                         \
        aA[ii] = *(const bf16x8*)(LDSb + (BUF) * 16384 + (KH) * 8192 + aoff[ii]); \
    }                                                                        \
    bq[0] = LDB(BUF, KH, (JP) * 2);                                          \
    bq[1] = LDB(BUF, KH, (JP) * 2 + 1);                                      \
    STAGE;                                                                   \
    asm volatile("s_waitcnt lgkmcnt(0)" ::: "memory");                       \
    SCB;                                                                     \
    __builtin_amdgcn_s_setprio(1);                                           \
    _Pragma("unroll")                                                        \
    for (int ii = 0; ii < 8; ii++) {                                         \
      acc[ii][(JP) * 2]     = MFMA_B16(aA[ii], bq[0], acc[ii][(JP) * 2], 0, 0, 0);     \
      acc[ii][(JP) * 2 + 1] = MFMA_B16(aA[ii], bq[1], acc[ii][(JP) * 2 + 1], 0, 0, 0); \
    }                                                                        \
    __builtin_amdgcn_s_setprio(0);                                           \
    SCB; VMS; SBAR; SCB;                                                     \
  }

__global__ __launch_bounds__(512, 2) void k_gemm256pv(
        const bf16* __restrict__ X, const bf16* __restrict__ Yt,
        const bf16* __restrict__ hsT, float* __restrict__ xgPart,
        float* __restrict__ rsPart,
        int K, int ldx, int ldy, long long sY, long long sHs) {
    __shared__ short LDSb[65536];        // 128 KiB (union with P tile)
    int id = blockIdx.x;
    int xcd = id & 7;
    int bx = (id >> 3) & 7;
    int group = (id >> 6) * 8 + xcd;
    int by = group & 7, z = group >> 3;
    const bf16* Xp = X;
    const bf16* Yp = Yt + (long long)z * sY;
    int tid = threadIdx.x;
    int m0 = bx * 256, n0 = by * 256;
    int wave = tid >> 6, lane = tid & 63;
    int wr = wave >> 2, wc = wave & 3;
    int fr = lane & 15, kq = lane >> 4;

    f32x4 zero = {0.f, 0.f, 0.f, 0.f};
    f32x4 acc[8][4];
    #pragma unroll
    for (int i = 0; i < 8; i++)
        #pragma unroll
        for (int j = 0; j < 4; j++) acc[i][j] = zero;

    auto SR = [&](int isA, int buf, int kh, int tile) {
        int rbase = (isA ? 0 : 32768) + buf * 16384 + kh * 8192;
        long long kb = (long long)tile * 64 + kh * 32;
        #pragma unroll
        for (int q = 0; q < 2; q++) {
            int pos = q * 512 + tid;
            int row = pos >> 2;
            int scol = ((pos & 3) ^ (row & 3) ^ ((row >> 2) & 3)) * 8;
            const bf16* g = (isA ? Xp + (long long)(m0 + row) * ldx
                                 : Yp + (long long)(n0 + row) * ldy) + kb + scol;
            glds16(g, LDSb + rbase + pos * 8);
        }
    };

    int aoff[8], boff[4];
    #pragma unroll
    for (int i = 0; i < 8; i++) {
        int row = wr * 128 + i * 16 + fr;
        aoff[i] = row * 32 + ((kq ^ (row & 3) ^ ((row >> 2) & 3)) << 3);
    }
    #pragma unroll
    for (int j = 0; j < 4; j++) {
        int row = wc * 64 + j * 16 + fr;
        boff[j] = row * 32 + ((kq ^ (row & 3) ^ ((row >> 2) & 3)) << 3);
    }

    bf16x8 aA[8], aB[8], bq[4];
    int NITER = K >> 7;                  // 2 tiles (2x BK=64) per iteration

    SR(1, 0, 0, 0); SR(0, 0, 0, 0);      // b0.A.kh0, b0.B.kh0 (tile 0)
    SR(1, 0, 1, 0); SR(0, 0, 1, 0);      // b0.A.kh1, b0.B.kh1 (tile 0)
    SR(1, 1, 0, 1); SR(0, 1, 0, 1);      // b1.A.kh0, b1.B.kh0 (tile 1)
    VM8;                                  // region (0,0) landed
    SBAR; SCB;
    #pragma unroll
    for (int ii = 0; ii < 8; ii++)        // prologue a-prefetch for pair 0
        aA[ii] = *(const bf16x8*)(LDSb + aoff[ii]);

    for (int i = 0; i < NITER - 1; i++) {
        int t1 = 2 * i + 1, t2 = 2 * i + 2, t3 = 2 * i + 3;
        SPAIR(0, 0, 0, 1, aA, aB, { SR(1, 1, 1, t1); }, { SR(0, 1, 1, t1); }, VM8, VM8)
        SPAIR(0, 1, 1, 0, aB, aA, { SR(1, 0, 0, t2); }, { SR(0, 0, 0, t2); }, VM8, VM8)
        SPAIR(1, 0, 1, 1, aA, aB, { SR(1, 0, 1, t2); }, { SR(0, 0, 1, t2); }, VM8, VM8)
        SPAIR(1, 1, 0, 0, aB, aA, { SR(1, 1, 0, t3); }, { SR(0, 1, 0, t3); }, VM8, VM8)
    }
    {   // final iteration: conservative phases (tail vmcnt too tight to prefetch)
        int t1 = 2 * NITER - 1;
        FPHASE(0, 0, 0, 0, { SR(1, 1, 1, t1); }, VM8)   // aA prefetched by loop
        FPHASE(0, 0, 1, 0, { SR(0, 1, 1, t1); }, VM8)
        FPHASE(0, 1, 0, 1, { }, VM8)
        FPHASE(0, 1, 1, 0, { }, VM4)
        FPHASE(1, 0, 0, 1, { }, VM4)
        FPHASE(1, 0, 1, 0, { }, VM0)
        FPHASE(1, 1, 0, 1, { }, VMN)
        FPHASE(1, 1, 1, 0, { }, VMN)
    }
    __syncthreads();   // all LDS reads retired; LDSb free for P tile

    // ---- epilogue 1: exp -> P (bf16) into LDS [256][256] swizzled; rowsums.
    int rq = kq * 4;   // D: col = lane&15, row = (lane>>4)*4 + reg  [m89-verified]
    #pragma unroll
    for (int i = 0; i < 8; i++) {
        #pragma unroll
        for (int r = 0; r < 4; r++) {
            int lrow = wr * 128 + i * 16 + rq + r;     // block-local n
            float rs = 0.f;
            #pragma unroll
            for (int j = 0; j < 4; j++) {
                int lcol = wc * 64 + j * 16 + fr;      // block-local p
                float e = (n0 + lcol < NN) ? __expf(acc[i][j][r]) : 0.f;
                bf16 bv = __float2bfloat16(e);
                int sl = (lcol >> 3) ^ (lrow & 7);
                LDSb[lrow * 256 + sl * 8 + (lcol & 7)] = *(short*)&bv;
                rs += e;
            }
            rs += __shfl_xor(rs, 1);
            rs += __shfl_xor(rs, 2);
            rs += __shfl_xor(rs, 4);
            rs += __shfl_xor(rs, 8);
            if (fr == 0)
                rsPart[((long long)z * 32 + by * 4 + wc) * NP + m0 + lrow] = rs;
        }
    }
    __syncthreads();

    // ---- epilogue 2: mini-GEMM xgp[n 256][j 128] = P @ hsT_z^T
    const bf16* hz = hsT + (long long)z * sHs;
    int wr2 = wave >> 2, wc2 = wave & 3;
    f32x4 acc2[8][2];
    #pragma unroll
    for (int i = 0; i < 8; i++)
        #pragma unroll
        for (int jj = 0; jj < 2; jj++) acc2[i][jj] = zero;
    #pragma unroll
    for (int ks = 0; ks < 8; ks++) {       // k = local p = ks*32
        bf16x8 a2[8], b2[2];
        #pragma unroll
        for (int i = 0; i < 8; i++) {
            int row = wr2 * 128 + i * 16 + fr;
            int sl = (ks * 4 + kq) ^ (row & 7);
            a2[i] = *(const bf16x8*)(LDSb + row * 256 + sl * 8);
        }
        #pragma unroll
        for (int jj = 0; jj < 2; jj++)
            b2[jj] = *(const bf16x8*)(hz + (long long)(wc2 * 32 + jj * 16 + fr) * NP
                                      + n0 + ks * 32 + kq * 8);
        #pragma unroll
        for (int i = 0; i < 8; i++)
            #pragma unroll
            for (int jj = 0; jj < 2; jj++)
                acc2[i][jj] = MFMA_B16(a2[i], b2[jj], acc2[i][jj], 0, 0, 0);
    }
    #pragma unroll
    for (int i = 0; i < 8; i++)
        #pragma unroll
        for (int jj = 0; jj < 2; jj++) {
            int jcol = wc2 * 32 + jj * 16 + fr;
            #pragma unroll
            for (int r = 0; r < 4; r++) {
                int n = m0 + wr2 * 128 + i * 16 + rq + r;
                xgPart[(long long)n * 8192 + by * 1024 + z * 128 + jcol] = acc2[i][jj][r];
            }
        }
}

// ---------------------------------------------------------------------------
// bf16 MFMA GEMM (m97 structure): C[M][N] = X[M][K] @ Yt[N][K]^T, fp32 out
// (optional bias+tanh epilogue). M,N mult of 128; K mult of 32*KSPLIT.
// ---------------------------------------------------------------------------
template<bool TANH, int KSPLIT>
__global__ __launch_bounds__(256) void k_gemm_bt(
        const bf16* __restrict__ X, const bf16* __restrict__ Yt,
        float* __restrict__ C, const float* __restrict__ bias,
        int K, int ldx, int ldy, int ldc,
        long long sX, long long sY, long long sC, long long sSlice) {
    __shared__ short As[128 * 32];
    __shared__ short Bs[128 * 32];
    int zz = blockIdx.z;
    int ks = 0;
    if (KSPLIT > 1) { ks = zz % KSPLIT; zz /= KSPLIT; }
    const bf16* Xp = X + (long long)zz * sX;
    const bf16* Yp = Yt + (long long)zz * sY;
    float* Cp = C + (long long)zz * sC + (long long)ks * sSlice;
    int tid = threadIdx.x;
    int m0 = blockIdx.x * 128, n0 = blockIdx.y * 128;
    int wave = tid >> 6, lane = tid & 63;
    int wm = (wave >> 1) * 64, wn = (wave & 1) * 64;
    int fr = lane & 15, kq = lane >> 4;

    f32x4 zero = {0.f, 0.f, 0.f, 0.f};
    f32x4 acc[4][4];
    #pragma unroll
    for (int i = 0; i < 4; i++)
        #pragma unroll
        for (int j = 0; j < 4; j++) acc[i][j] = zero;

    int lrow = lane >> 2, lcol = (lane & 3) * 8;
    const bf16* xg0 = Xp + (long long)(m0 + wave * 16 + lrow) * ldx + lcol;
    const bf16* xg1 = xg0 + (long long)64 * ldx;
    const bf16* yg0 = Yp + (long long)(n0 + wave * 16 + lrow) * ldy + lcol;
    const bf16* yg1 = yg0 + (long long)64 * ldy;
    short* lA0 = As + wave * 512;          // rows wave*16..+15
    short* lA1 = As + (wave + 4) * 512;    // rows 64+wave*16..+15
    short* lB0 = Bs + wave * 512;
    short* lB1 = Bs + (wave + 4) * 512;

    int kbeg = (KSPLIT > 1) ? ks * (K / KSPLIT) : 0;
    int kend = kbeg + K / KSPLIT;
    for (int k0 = kbeg; k0 < kend; k0 += 32) {
        __syncthreads();                   // prev iter's LDS reads done
        glds16(xg0 + k0, lA0);
        glds16(xg1 + k0, lA1);
        glds16(yg0 + k0, lB0);
        glds16(yg1 + k0, lB1);
        __syncthreads();                   // vmcnt(0) drained by compiler
        bf16x8 a[4], b[4];
        #pragma unroll
        for (int i = 0; i < 4; i++)
            a[i] = *(const bf16x8*)(As + (wm + i * 16 + fr) * 32 + kq * 8);
        #pragma unroll
        for (int j = 0; j < 4; j++)
            b[j] = *(const bf16x8*)(Bs + (wn + j * 16 + fr) * 32 + kq * 8);
        #pragma unroll
        for (int i = 0; i < 4; i++)
            #pragma unroll
            for (int j = 0; j < 4; j++)
                acc[i][j] = __builtin_amdgcn_mfma_f32_16x16x32_bf16(a[i], b[j], acc[i][j], 0, 0, 0);
    }
    int rq = kq * 4;   // D: col = lane&15, row = (lane>>4)*4 + reg  [m89-verified]
    for (int i = 0; i < 4; i++)
        for (int j = 0; j < 4; j++) {
            int col = n0 + wn + j * 16 + fr;
            float bv = TANH ? bias[col] : 0.0f;
            #pragma unroll
            for (int r = 0; r < 4; r++) {
                int row = m0 + wm + i * 16 + rq + r;
                float v = acc[i][j][r];
                Cp[(long long)row * ldc + col] =
                    TANH ? 0.1f * fast_tanh(v + bv) : v;
            }
        }
}

// ---------------------------------------------------------------------------
// g[b][n][o] = bias_n[o] + inv[b][n] * sum_j xg[b][n][j] * Wn[j][o]  (bf16)
// ---------------------------------------------------------------------------
__global__ __launch_bounds__(256) void k_g(
        const float* __restrict__ Wn_all, const float* __restrict__ bp,
        const float* __restrict__ emb, const float* __restrict__ xgPart,
        const float* __restrict__ rsPart, bf16* __restrict__ gbf) {
    __shared__ float Wn[8192];       // [j][o] 32KB
    __shared__ float xgs[1024];      // [b][j] (already inv-scaled)
    __shared__ float biass[64];
    __shared__ float invs[8];
    __shared__ float rsred[256];
    int n = blockIdx.x, t = threadIdx.x;
    rsred[t] = rsPart[(size_t)t * NP + n];   // slab t, column n
    if (t >= 64 && t < 128) {
        int o = t - 64;
        float a = 0.f;
        #pragma unroll
        for (int d = 0; d < 16; d++) a += emb[n * 16 + d] * bp[d * 64 + o];
        biass[o] = a;
    }
    {
        const f32x4* src = (const f32x4*)(Wn_all + (size_t)n * 8192);
        f32x4* dst = (f32x4*)Wn;
        #pragma unroll
        for (int s = 0; s < 8; s++) dst[s * 256 + t] = src[s * 256 + t];
    }
    __syncthreads();
    if (t < 8) {
        float s = 0.f;
        #pragma unroll
        for (int y = 0; y < 32; y++) s += rsred[t * 32 + y];  // same order as before
        invs[t] = 1.0f / s;
    }
    __syncthreads();
    for (int s = 0; s < 4; s++) {
        int id = t + s * 256;
        int b = id >> 7, j = id & 127;
        const float* xp = xgPart + (size_t)n * 8192 + b * 128 + j;
        float a = xp[0];
        #pragma unroll
        for (int by = 1; by < 8; by++) a += xp[by * 1024];
        xgs[id] = a * invs[b];
    }
    __syncthreads();
    int o = t & 63, bh = t >> 6;
    for (int half = 0; half < 2; half++) {
        int b = bh + half * 4;
        float a = biass[o];
        for (int j = 0; j < 128; j++) a += xgs[b * 128 + j] * Wn[j * 64 + o];
        gbf[((size_t)b * NN + n) * 64 + o] = __float2bfloat16(a);
    }
}

// ---------------------------------------------------------------------------
extern "C" void kernel_launch(void* const* d_in, const int* in_sizes, int n_in,
                              void* d_out, int out_size, void* d_ws, size_t ws_size,
                              hipStream_t stream) {
    const float* z     = (const float*)d_in[0];
    const float* W_in  = (const float*)d_in[1];
    const float* b_in  = (const float*)d_in[2];
    const float* W_out = (const float*)d_in[3];
    const float* b_out = (const float*)d_in[4];
    const float* emb   = (const float*)d_in[5];
    const float* wp    = (const float*)d_in[6];
    const float* bp    = (const float*)d_in[7];
    const float* w1    = (const float*)d_in[8];
    const float* w2    = (const float*)d_in[9];
    const float* vs    = (const float*)d_in[10];
    const float* bs    = (const float*)d_in[11];

    char* p = (char*)d_ws;
    auto alloc = [&](size_t bytes) -> char* {
        char* r = p;
        p += (bytes + 255) & ~(size_t)255;
        return r;
    };
    float* h       = (float*)alloc((size_t)BB * NN * 64 * 4);          // 4.1 MB
    float* e1      = (float*)alloc((size_t)BB * NN * 4);
    float* e2      = (float*)alloc((size_t)BB * NN * 4);
    bf16*  A_bf    = (bf16*) alloc((size_t)NP * NP * 2);               // 8.4 MB
    bf16*  vs_bf   = (bf16*) alloc((size_t)NP * NP * 2);               // 8.4 MB
    bf16*  Tt_all  = (bf16*) alloc((size_t)BB * NP * NP * 2);          // 67 MB
    float* rsPart  = (float*)alloc((size_t)BB * 32 * NP * 4);          // 2.1 MB
    bf16*  hTcat   = (bf16*) alloc((size_t)512 * NP * 2);              // 2.1 MB
    float* AhPart  = (float*)alloc((size_t)4 * NP * 512 * 4);          // 16.8 MB
    bf16*  hsT     = (bf16*) alloc((size_t)BB * 128 * NP * 2);         // 4.2 MB
    float* xgPart  = (float*)alloc((size_t)NP * 8192 * 4);             // 67 MB ([n][by][z][j])
    bf16*  gbf     = (bf16*) alloc((size_t)BB * NN * 64 * 2);          // 2.0 MB
    bf16*  Wo_bf   = (bf16*) alloc((size_t)4096 * 64 * 2);             // 0.5 MB
    float* Wn_all  = (float*)alloc((size_t)NN * 8192 * 4);             // 65.5 MB

    k_h<<<BB * NN / 8, 256, 0, stream>>>(z, W_in, b_in, w1, w2, h, e1, e2);

    // mega: Tt(1024) | cvt_vs(16384) | A(2048) | wn(512) | hT(256) | wout(1024)
    k_mega<<<1024 + 16384 + 2048 + 512 + 256 + 1024, 256, 0, stream>>>(
        e1, e2, bs, Tt_all, vs, vs_bf, emb, A_bf, wp, Wn_all,
        h, hTcat, hsT, W_out, Wo_bf);

    // Ahcat[n][b*64+c] = sum_m A[n][m] h[b][m][c] -- K-split x4 (256 wg)
    k_gemm_bt<false, 4><<<dim3(16, 4, 4), 256, 0, stream>>>(
        A_bf, hTcat, AhPart, nullptr, NP, NP, NP, 512,
        0, 0, 0, (long long)NP * 512);
    k_redT<<<dim3(NP / 64, BB), 256, 0, stream>>>(AhPart, hsT);

    // fused {M = vs@T, P = exp(M), rowsums, xg partial = P@hs}, 8-phase,
    // XCD-locality swizzle + a-fragment prefetch
    k_gemm256pv<<<512, 512, 0, stream>>>(
        vs_bf, Tt_all, hsT, xgPart, rsPart, NP, NP, NP,
        (long long)NP * NP, (long long)128 * NP);

    k_g<<<NN, 256, 0, stream>>>(Wn_all, bp, emb, xgPart, rsPart, gbf);
    // out[bn][o] = 0.1*tanh(g[bn] . W_out[o] + b_out[o]);  16000 = 125*128
    k_gemm_bt<true, 1><<<dim3(125, 32, 1), 256, 0, stream>>>(
        gbf, Wo_bf, (float*)d_out, b_out, 64, 64, 64, 4096, 0, 0, 0, 0);
}

// Round 14
// 585.814 us; speedup vs baseline: 1.0365x; 1.0365x over previous
//
#include <hip/hip_runtime.h>
#include <hip/hip_bf16.h>

#define NN 2000   // nodes
#define NP 2048   // padded
#define BB 8
#define HH 64
#define DD 16

typedef __hip_bfloat16 bf16;
typedef short bf16x8 __attribute__((ext_vector_type(8)));  // 8 bf16 in 4 VGPRs
typedef float f32x4 __attribute__((ext_vector_type(4)));

__device__ __forceinline__ float fast_sigmoid(float x) {
    return 1.0f / (1.0f + __expf(-x));
}
__device__ __forceinline__ float fast_tanh(float x) {
    float e = __expf(2.0f * x);           // inf-safe: x>>0 -> 1, x<<0 -> -1
    return 1.0f - 2.0f / (e + 1.0f);
}

// async 16B global->LDS. LDS dest = wave-uniform base + lane*16 (m97/m104).
__device__ __forceinline__ void glds16(const void* g, void* l) {
    __builtin_amdgcn_global_load_lds(
        (const __attribute__((address_space(1))) void*)g,
        (__attribute__((address_space(3))) void*)l, 16, 0, 0);
}

// ---------------------------------------------------------------------------
// h = relu(z @ W_in^T + b_in); e1 = h@w1, e2 = h@w2.
// 8 rows per block (W_in staging amortized 8x). Per-row math bit-identical.
// ---------------------------------------------------------------------------
__global__ __launch_bounds__(256) void k_h(
        const float* __restrict__ z, const float* __restrict__ W_in,
        const float* __restrict__ b_in, const float* __restrict__ w1,
        const float* __restrict__ w2, float* __restrict__ h,
        float* __restrict__ e1, float* __restrict__ e2) {
    __shared__ float WT[64 * 65];
    __shared__ float zs[8][64];
    int t = threadIdx.x;
    int lane = t & 63, ty = t >> 6;
    int bn0 = blockIdx.x * 8;
    for (int i = t; i < 64 * 64; i += 256) {
        int hh = i >> 6, c = i & 63;
        WT[c * 65 + hh] = W_in[i];           // WT[c][h] = W_in[h][c]
    }
    #pragma unroll
    for (int q = 0; q < 2; q++) {
        int r = ty * 2 + q;
        zs[r][lane] = z[(size_t)(bn0 + r) * 64 + lane];
    }
    __syncthreads();
    #pragma unroll
    for (int q = 0; q < 2; q++) {
        int r = ty * 2 + q;
        float acc = b_in[lane];
        #pragma unroll
        for (int c = 0; c < 64; c++) acc += zs[r][c] * WT[c * 65 + lane];
        float hv = fmaxf(acc, 0.0f);
        h[(size_t)(bn0 + r) * 64 + lane] = hv;
        float p1 = hv * w1[lane], p2 = hv * w2[lane];
        #pragma unroll
        for (int off = 32; off > 0; off >>= 1) {
            p1 += __shfl_down(p1, off);
            p2 += __shfl_down(p2, off);
        }
        if (lane == 0) { e1[bn0 + r] = p1; e2[bn0 + r] = p2; }
    }
}

// ---------------------------------------------------------------------------
// MEGA kernel: one launch for all mid-size independent work (R11, unchanged).
// ---------------------------------------------------------------------------
__global__ __launch_bounds__(256) void k_mega(
        const float* __restrict__ e1, const float* __restrict__ e2,
        const float* __restrict__ bs, bf16* __restrict__ Tt,
        const float* __restrict__ vs, bf16* __restrict__ vs_bf,
        const float* __restrict__ emb, bf16* __restrict__ A,
        const float* __restrict__ wp, float* __restrict__ Wn_all,
        const float* __restrict__ h, bf16* __restrict__ hTcat,
        bf16* __restrict__ hsT,
        const float* __restrict__ W_out, bf16* __restrict__ Wo_bf) {
    __shared__ float smem[4160];
    int bid = blockIdx.x, t = threadIdx.x;

    if (bid < 1024) {                    // ---- k_Tt, all 8 batches per tile
        int mt = bid & 31, pt = bid >> 5;
        float* tile = smem;              // tile[i_m*65 + tx_p] = bs[m0+i][p0+tx]
        int tx = t & 63, ty = t >> 6;
        int m0 = mt * 64, p0 = pt * 64;
        for (int i = ty * 16; i < ty * 16 + 16; i++) {
            int m = m0 + i, p = p0 + tx;
            tile[i * 65 + tx] = (m < NN && p < NN) ? bs[(size_t)m * NN + p] : 0.0f;
        }
        __syncthreads();                 // tile read-only from here: no more syncs
        int m = m0 + tx;
        for (int b = 0; b < BB; b++) {
            float e1v = (m < NN) ? e1[b * NN + m] : 0.0f;
            bf16* Tb = Tt + (size_t)b * NP * NP;
            for (int i = ty * 16; i < ty * 16 + 16; i++) {
                int p = p0 + i;
                float v = 0.0f;
                if (m < NN && p < NN)
                    v = fast_sigmoid(e1v * e2[b * NN + p] + tile[tx * 65 + i]);
                Tb[((size_t)p) * NP + m] = __float2bfloat16(v);
            }
        }
        return;
    }
    bid -= 1024;
    if (bid < 16384) {                   // ---- cvt_vs
        int id = bid * 256 + t;
        int n = id >> 11, m = id & (NP - 1);
        float v = (n < NN && m < NN) ? vs[n * NN + m] : 0.0f;
        vs_bf[id] = __float2bfloat16(v);
        return;
    }
    bid -= 16384;
    if (bid < 2048) {                    // ---- k_A
        int i = bid;
        if (i >= NN) {
            for (int j = t; j < NP; j += 256) A[(size_t)i * NP + j] = __float2bfloat16(0.0f);
            return;
        }
        float* rowbuf = smem;            // 2048
        float* red = smem + 2048;        // 256
        float* ei = smem + 2304;         // 16
        if (t < DD) ei[t] = emb[i * DD + t];
        __syncthreads();
        float lmax = -1e30f;
        for (int j = t; j < NP; j += 256) {
            float s = 0.0f;
            if (j < NN) {
                #pragma unroll
                for (int d = 0; d < DD; d++) s += ei[d] * emb[j * DD + d];
                s = fmaxf(s, 0.0f);
                lmax = fmaxf(lmax, s);
            }
            rowbuf[j] = s;
        }
        red[t] = lmax; __syncthreads();
        for (int o = 128; o > 0; o >>= 1) { if (t < o) red[t] = fmaxf(red[t], red[t + o]); __syncthreads(); }
        float mx = red[0];
        __syncthreads();
        float lsum = 0.0f;
        for (int j = t; j < NN; j += 256) {
            float e = __expf(rowbuf[j] - mx);
            rowbuf[j] = e; lsum += e;
        }
        red[t] = lsum; __syncthreads();
        for (int o = 128; o > 0; o >>= 1) { if (t < o) red[t] += red[t + o]; __syncthreads(); }
        float inv = 1.0f / red[0];
        for (int j = t; j < NP; j += 256)
            A[(size_t)i * NP + j] = __float2bfloat16(j < NN ? rowbuf[j] * inv : 0.0f);
        return;
    }
    bid -= 2048;
    if (bid < 512) {                     // ---- k_wn
        float* embs = smem;              // 2048
        int n0 = (bid & 15) * 128;
        int jo = (bid >> 4) * 256 + t;   // j*64+o, < 8192
        float wv[16];
        #pragma unroll
        for (int d = 0; d < 16; d++) wv[d] = wp[(size_t)d * 8192 + jo];
        for (int s = t; s < 128 * 16; s += 256) {
            int i = s >> 4, d = s & 15;
            int n = n0 + i;
            embs[s] = (n < NN) ? emb[n * 16 + d] : 0.f;
        }
        __syncthreads();
        for (int i = 0; i < 128; i++) {
            int n = n0 + i;
            if (n >= NN) break;
            const f32x4* ev = (const f32x4*)&embs[i * 16];
            f32x4 ea = ev[0], eb = ev[1], ec = ev[2], ed = ev[3];
            float a = 0.f;
            #pragma unroll
            for (int q = 0; q < 4; q++) a += ea[q] * wv[q];
            #pragma unroll
            for (int q = 0; q < 4; q++) a += eb[q] * wv[4 + q];
            #pragma unroll
            for (int q = 0; q < 4; q++) a += ec[q] * wv[8 + q];
            #pragma unroll
            for (int q = 0; q < 4; q++) a += ed[q] * wv[12 + q];
            Wn_all[(size_t)n * 8192 + jo] = a;
        }
        return;
    }
    bid -= 512;
    if (bid < 256) {                     // ---- k_hT
        float* tile = smem;
        int nt = bid & 31, b = bid >> 5;
        int tx = t & 63, ty = t >> 6;
        int n0 = nt * 64;
        for (int i = ty * 16; i < ty * 16 + 16; i++) {
            int n = n0 + i;
            tile[i * 65 + tx] = (n < NN) ? h[((size_t)b * NN + n) * 64 + tx] : 0.0f;
        }
        __syncthreads();
        for (int i = ty * 16; i < ty * 16 + 16; i++) {
            bf16 v = __float2bfloat16(tile[tx * 65 + i]);   // h[b][n0+tx][i]
            hTcat[((size_t)b * 64 + i) * NP + n0 + tx] = v;
            hsT[((size_t)b * 128 + i) * NP + n0 + tx] = v;
        }
        return;
    }
    bid -= 256;
    {                                    // ---- cvt_wout (1024 blocks)
        int id = bid * 256 + t;          // 4096*64
        Wo_bf[id] = __float2bfloat16(W_out[id]);
    }
}

// ---------------------------------------------------------------------------
// merged reduce4 + transpose: hsT[b*128+64+c][p] = sum_sl AhPart[sl][p][b*64+c]
// ---------------------------------------------------------------------------
__global__ __launch_bounds__(256) void k_redT(const float* __restrict__ AhPart,
                                              bf16* __restrict__ hsT) {
    __shared__ float tile[64 * 65];
    int pt = blockIdx.x, b = blockIdx.y;
    int tx = threadIdx.x & 63, ty = threadIdx.x >> 6;
    int p0 = pt * 64, q0 = b * 64;
    const long long TOT = (long long)NP * 512;
    for (int i = ty * 16; i < ty * 16 + 16; i++) {
        long long base = ((long long)p0 + i) * 512 + q0 + tx;
        float s = AhPart[base];
        #pragma unroll
        for (int sl = 1; sl < 4; sl++) s += AhPart[sl * TOT + base];
        tile[i * 65 + tx] = s;
    }
    __syncthreads();
    for (int i = ty * 16; i < ty * 16 + 16; i++)
        hsT[((size_t)b * 128 + 64 + i) * NP + p0 + tx] =
            __float2bfloat16(tile[tx * 65 + i]);
}

// ---------------------------------------------------------------------------
// 256x256-tile bf16 MFMA GEMM, m201-style 8-phase REGION-PARTITIONED pipeline
// (R10, frozen) + XCD-LOCALITY SWIZZLE (R12): 1-D grid of 512; decode
// xcd=id&7, bx=(id>>3)&7, group=(id>>6)*8+xcd, (by,z)=(group&7,group>>3):
// all 8 bx-members of a (by,z) group land on ONE XCD -> B fetched once.
// R13's a-fragment prefetch REVERTED (regressed 588.7->607.2: +32 VGPR and
// hand-counted lgkmcnt defeated the compiler's own fine-grained scheduling).
// FUSED epilogue: P=bf16(exp(acc))->LDS, rowsums, PV.
// ---------------------------------------------------------------------------
#define MFMA_B16 __builtin_amdgcn_mfma_f32_16x16x32_bf16
#define VM8 asm volatile("s_waitcnt vmcnt(8)" ::: "memory")
#define VM4 asm volatile("s_waitcnt vmcnt(4)" ::: "memory")
#define VM0 asm volatile("s_waitcnt vmcnt(0)" ::: "memory")
#define VMN
#define PHASE(BUF, KH, JP, READA, STAGE, VMS)                                \
  {                                                                          \
    if (READA) {                                                             \
      _Pragma("unroll")                                                      \
      for (int ii = 0; ii < 8; ii++)                                         \
        a[ii] = *(const bf16x8*)(LDSb + (BUF) * 16384 + (KH) * 8192 + aoff[ii]); \
    }                                                                        \
    b[0] = *(const bf16x8*)(LDSb + 32768 + (BUF) * 16384 + (KH) * 8192 + boff[(JP) * 2]); \
    b[1] = *(const bf16x8*)(LDSb + 32768 + (BUF) * 16384 + (KH) * 8192 + boff[(JP) * 2 + 1]); \
    STAGE;                                                                   \
    asm volatile("s_waitcnt lgkmcnt(0)" ::: "memory");                       \
    __builtin_amdgcn_sched_barrier(0);                                       \
    __builtin_amdgcn_s_setprio(1);                                           \
    _Pragma("unroll")                                                        \
    for (int ii = 0; ii < 8; ii++) {                                         \
      acc[ii][(JP) * 2]     = MFMA_B16(a[ii], b[0], acc[ii][(JP) * 2], 0, 0, 0);     \
      acc[ii][(JP) * 2 + 1] = MFMA_B16(a[ii], b[1], acc[ii][(JP) * 2 + 1], 0, 0, 0); \
    }                                                                        \
    __builtin_amdgcn_s_setprio(0);                                           \
    __builtin_amdgcn_sched_barrier(0);                                       \
    VMS;                                                                     \
    __builtin_amdgcn_s_barrier();                                            \
    __builtin_amdgcn_sched_barrier(0);                                       \
  }

__global__ __launch_bounds__(512, 2) void k_gemm256pv(
        const bf16* __restrict__ X, const bf16* __restrict__ Yt,
        const bf16* __restrict__ hsT, float* __restrict__ xgPart,
        float* __restrict__ rsPart,
        int K, int ldx, int ldy, long long sY, long long sHs) {
    __shared__ short LDSb[65536];        // 128 KiB (union with P tile)
    int id = blockIdx.x;
    int xcd = id & 7;
    int bx = (id >> 3) & 7;
    int group = (id >> 6) * 8 + xcd;
    int by = group & 7, z = group >> 3;
    const bf16* Xp = X;
    const bf16* Yp = Yt + (long long)z * sY;
    int tid = threadIdx.x;
    int m0 = bx * 256, n0 = by * 256;
    int wave = tid >> 6, lane = tid & 63;
    int wr = wave >> 2, wc = wave & 3;
    int fr = lane & 15, kq = lane >> 4;

    f32x4 zero = {0.f, 0.f, 0.f, 0.f};
    f32x4 acc[8][4];
    #pragma unroll
    for (int i = 0; i < 8; i++)
        #pragma unroll
        for (int j = 0; j < 4; j++) acc[i][j] = zero;

    auto SR = [&](int isA, int buf, int kh, int tile) {
        int rbase = (isA ? 0 : 32768) + buf * 16384 + kh * 8192;
        long long kb = (long long)tile * 64 + kh * 32;
        #pragma unroll
        for (int q = 0; q < 2; q++) {
            int pos = q * 512 + tid;
            int row = pos >> 2;
            int scol = ((pos & 3) ^ (row & 3) ^ ((row >> 2) & 3)) * 8;
            const bf16* g = (isA ? Xp + (long long)(m0 + row) * ldx
                                 : Yp + (long long)(n0 + row) * ldy) + kb + scol;
            glds16(g, LDSb + rbase + pos * 8);
        }
    };

    int aoff[8], boff[4];
    #pragma unroll
    for (int i = 0; i < 8; i++) {
        int row = wr * 128 + i * 16 + fr;
        aoff[i] = row * 32 + ((kq ^ (row & 3) ^ ((row >> 2) & 3)) << 3);
    }
    #pragma unroll
    for (int j = 0; j < 4; j++) {
        int row = wc * 64 + j * 16 + fr;
        boff[j] = row * 32 + ((kq ^ (row & 3) ^ ((row >> 2) & 3)) << 3);
    }

    bf16x8 a[8], b[2];
    int NITER = K >> 7;                  // 2 tiles (2x BK=64) per iteration

    SR(1, 0, 0, 0); SR(0, 0, 0, 0);      // b0.A.kh0, b0.B.kh0 (tile 0)
    SR(1, 0, 1, 0); SR(0, 0, 1, 0);      // b0.A.kh1, b0.B.kh1 (tile 0)
    SR(1, 1, 0, 1); SR(0, 1, 0, 1);      // b1.A.kh0, b1.B.kh0 (tile 1)
    VM8;
    __builtin_amdgcn_s_barrier();
    __builtin_amdgcn_sched_barrier(0);

    for (int i = 0; i < NITER - 1; i++) {
        int t1 = 2 * i + 1, t2 = 2 * i + 2, t3 = 2 * i + 3;
        PHASE(0, 0, 0, 1, { SR(1, 1, 1, t1); }, VM8)
        PHASE(0, 0, 1, 0, { SR(0, 1, 1, t1); }, VM8)
        PHASE(0, 1, 0, 1, { SR(1, 0, 0, t2); }, VM8)
        PHASE(0, 1, 1, 0, { SR(0, 0, 0, t2); }, VM8)
        PHASE(1, 0, 0, 1, { SR(1, 0, 1, t2); }, VM8)
        PHASE(1, 0, 1, 0, { SR(0, 0, 1, t2); }, VM8)
        PHASE(1, 1, 0, 1, { SR(1, 1, 0, t3); }, VM8)
        PHASE(1, 1, 1, 0, { SR(0, 1, 0, t3); }, VM8)
    }
    {
        int t1 = 2 * NITER - 1;
        PHASE(0, 0, 0, 1, { SR(1, 1, 1, t1); }, VM8)
        PHASE(0, 0, 1, 0, { SR(0, 1, 1, t1); }, VM8)
        PHASE(0, 1, 0, 1, { }, VM8)
        PHASE(0, 1, 1, 0, { }, VM4)
        PHASE(1, 0, 0, 1, { }, VM4)
        PHASE(1, 0, 1, 0, { }, VM0)
        PHASE(1, 1, 0, 1, { }, VMN)
        PHASE(1, 1, 1, 0, { }, VMN)
    }
    __syncthreads();   // all LDS reads retired; LDSb free for P tile

    // ---- epilogue 1: exp -> P (bf16) into LDS [256][256] swizzled; rowsums.
    int rq = kq * 4;   // D: col = lane&15, row = (lane>>4)*4 + reg  [m89-verified]
    #pragma unroll
    for (int i = 0; i < 8; i++) {
        #pragma unroll
        for (int r = 0; r < 4; r++) {
            int lrow = wr * 128 + i * 16 + rq + r;     // block-local n
            float rs = 0.f;
            #pragma unroll
            for (int j = 0; j < 4; j++) {
                int lcol = wc * 64 + j * 16 + fr;      // block-local p
                float e = (n0 + lcol < NN) ? __expf(acc[i][j][r]) : 0.f;
                bf16 bv = __float2bfloat16(e);
                int sl = (lcol >> 3) ^ (lrow & 7);
                LDSb[lrow * 256 + sl * 8 + (lcol & 7)] = *(short*)&bv;
                rs += e;
            }
            rs += __shfl_xor(rs, 1);
            rs += __shfl_xor(rs, 2);
            rs += __shfl_xor(rs, 4);
            rs += __shfl_xor(rs, 8);
            if (fr == 0)
                rsPart[((long long)z * 32 + by * 4 + wc) * NP + m0 + lrow] = rs;
        }
    }
    __syncthreads();

    // ---- epilogue 2: mini-GEMM xgp[n 256][j 128] = P @ hsT_z^T
    const bf16* hz = hsT + (long long)z * sHs;
    int wr2 = wave >> 2, wc2 = wave & 3;
    f32x4 acc2[8][2];
    #pragma unroll
    for (int i = 0; i < 8; i++)
        #pragma unroll
        for (int jj = 0; jj < 2; jj++) acc2[i][jj] = zero;
    #pragma unroll
    for (int ks = 0; ks < 8; ks++) {       // k = local p = ks*32
        bf16x8 a2[8], b2[2];
        #pragma unroll
        for (int i = 0; i < 8; i++) {
            int row = wr2 * 128 + i * 16 + fr;
            int sl = (ks * 4 + kq) ^ (row & 7);
            a2[i] = *(const bf16x8*)(LDSb + row * 256 + sl * 8);
        }
        #pragma unroll
        for (int jj = 0; jj < 2; jj++)
            b2[jj] = *(const bf16x8*)(hz + (long long)(wc2 * 32 + jj * 16 + fr) * NP
                                      + n0 + ks * 32 + kq * 8);
        #pragma unroll
        for (int i = 0; i < 8; i++)
            #pragma unroll
            for (int jj = 0; jj < 2; jj++)
                acc2[i][jj] = MFMA_B16(a2[i], b2[jj], acc2[i][jj], 0, 0, 0);
    }
    #pragma unroll
    for (int i = 0; i < 8; i++)
        #pragma unroll
        for (int jj = 0; jj < 2; jj++) {
            int jcol = wc2 * 32 + jj * 16 + fr;
            #pragma unroll
            for (int r = 0; r < 4; r++) {
                int n = m0 + wr2 * 128 + i * 16 + rq + r;
                xgPart[(long long)n * 8192 + by * 1024 + z * 128 + jcol] = acc2[i][jj][r];
            }
        }
}

// ---------------------------------------------------------------------------
// bf16 MFMA GEMM (m97 structure): C[M][N] = X[M][K] @ Yt[N][K]^T, fp32 out
// (optional bias+tanh epilogue). M,N mult of 128; K mult of 32*KSPLIT.
// ---------------------------------------------------------------------------
template<bool TANH, int KSPLIT>
__global__ __launch_bounds__(256) void k_gemm_bt(
        const bf16* __restrict__ X, const bf16* __restrict__ Yt,
        float* __restrict__ C, const float* __restrict__ bias,
        int K, int ldx, int ldy, int ldc,
        long long sX, long long sY, long long sC, long long sSlice) {
    __shared__ short As[128 * 32];
    __shared__ short Bs[128 * 32];
    int zz = blockIdx.z;
    int ks = 0;
    if (KSPLIT > 1) { ks = zz % KSPLIT; zz /= KSPLIT; }
    const bf16* Xp = X + (long long)zz * sX;
    const bf16* Yp = Yt + (long long)zz * sY;
    float* Cp = C + (long long)zz * sC + (long long)ks * sSlice;
    int tid = threadIdx.x;
    int m0 = blockIdx.x * 128, n0 = blockIdx.y * 128;
    int wave = tid >> 6, lane = tid & 63;
    int wm = (wave >> 1) * 64, wn = (wave & 1) * 64;
    int fr = lane & 15, kq = lane >> 4;

    f32x4 zero = {0.f, 0.f, 0.f, 0.f};
    f32x4 acc[4][4];
    #pragma unroll
    for (int i = 0; i < 4; i++)
        #pragma unroll
        for (int j = 0; j < 4; j++) acc[i][j] = zero;

    int lrow = lane >> 2, lcol = (lane & 3) * 8;
    const bf16* xg0 = Xp + (long long)(m0 + wave * 16 + lrow) * ldx + lcol;
    const bf16* xg1 = xg0 + (long long)64 * ldx;
    const bf16* yg0 = Yp + (long long)(n0 + wave * 16 + lrow) * ldy + lcol;
    const bf16* yg1 = yg0 + (long long)64 * ldy;
    short* lA0 = As + wave * 512;          // rows wave*16..+15
    short* lA1 = As + (wave + 4) * 512;    // rows 64+wave*16..+15
    short* lB0 = Bs + wave * 512;
    short* lB1 = Bs + (wave + 4) * 512;

    int kbeg = (KSPLIT > 1) ? ks * (K / KSPLIT) : 0;
    int kend = kbeg + K / KSPLIT;
    for (int k0 = kbeg; k0 < kend; k0 += 32) {
        __syncthreads();                   // prev iter's LDS reads done
        glds16(xg0 + k0, lA0);
        glds16(xg1 + k0, lA1);
        glds16(yg0 + k0, lB0);
        glds16(yg1 + k0, lB1);
        __syncthreads();                   // vmcnt(0) drained by compiler
        bf16x8 a[4], b[4];
        #pragma unroll
        for (int i = 0; i < 4; i++)
            a[i] = *(const bf16x8*)(As + (wm + i * 16 + fr) * 32 + kq * 8);
        #pragma unroll
        for (int j = 0; j < 4; j++)
            b[j] = *(const bf16x8*)(Bs + (wn + j * 16 + fr) * 32 + kq * 8);
        #pragma unroll
        for (int i = 0; i < 4; i++)
            #pragma unroll
            for (int j = 0; j < 4; j++)
                acc[i][j] = __builtin_amdgcn_mfma_f32_16x16x32_bf16(a[i], b[j], acc[i][j], 0, 0, 0);
    }
    int rq = kq * 4;   // D: col = lane&15, row = (lane>>4)*4 + reg  [m89-verified]
    for (int i = 0; i < 4; i++)
        for (int j = 0; j < 4; j++) {
            int col = n0 + wn + j * 16 + fr;
            float bv = TANH ? bias[col] : 0.0f;
            #pragma unroll
            for (int r = 0; r < 4; r++) {
                int row = m0 + wm + i * 16 + rq + r;
                float v = acc[i][j][r];
                Cp[(long long)row * ldc + col] =
                    TANH ? 0.1f * fast_tanh(v + bv) : v;
            }
        }
}

// ---------------------------------------------------------------------------
// g[b][n][o] = bias_n[o] + inv[b][n] * sum_j xg[b][n][j] * Wn[j][o]  (bf16)
// ---------------------------------------------------------------------------
__global__ __launch_bounds__(256) void k_g(
        const float* __restrict__ Wn_all, const float* __restrict__ bp,
        const float* __restrict__ emb, const float* __restrict__ xgPart,
        const float* __restrict__ rsPart, bf16* __restrict__ gbf) {
    __shared__ float Wn[8192];       // [j][o] 32KB
    __shared__ float xgs[1024];      // [b][j] (already inv-scaled)
    __shared__ float biass[64];
    __shared__ float invs[8];
    __shared__ float rsred[256];
    int n = blockIdx.x, t = threadIdx.x;
    rsred[t] = rsPart[(size_t)t * NP + n];   // slab t, column n
    if (t >= 64 && t < 128) {
        int o = t - 64;
        float a = 0.f;
        #pragma unroll
        for (int d = 0; d < 16; d++) a += emb[n * 16 + d] * bp[d * 64 + o];
        biass[o] = a;
    }
    {
        const f32x4* src = (const f32x4*)(Wn_all + (size_t)n * 8192);
        f32x4* dst = (f32x4*)Wn;
        #pragma unroll
        for (int s = 0; s < 8; s++) dst[s * 256 + t] = src[s * 256 + t];
    }
    __syncthreads();
    if (t < 8) {
        float s = 0.f;
        #pragma unroll
        for (int y = 0; y < 32; y++) s += rsred[t * 32 + y];  // same order as before
        invs[t] = 1.0f / s;
    }
    __syncthreads();
    for (int s = 0; s < 4; s++) {
        int id = t + s * 256;
        int b = id >> 7, j = id & 127;
        const float* xp = xgPart + (size_t)n * 8192 + b * 128 + j;
        float a = xp[0];
        #pragma unroll
        for (int by = 1; by < 8; by++) a += xp[by * 1024];
        xgs[id] = a * invs[b];
    }
    __syncthreads();
    int o = t & 63, bh = t >> 6;
    for (int half = 0; half < 2; half++) {
        int b = bh + half * 4;
        float a = biass[o];
        for (int j = 0; j < 128; j++) a += xgs[b * 128 + j] * Wn[j * 64 + o];
        gbf[((size_t)b * NN + n) * 64 + o] = __float2bfloat16(a);
    }
}

// ---------------------------------------------------------------------------
extern "C" void kernel_launch(void* const* d_in, const int* in_sizes, int n_in,
                              void* d_out, int out_size, void* d_ws, size_t ws_size,
                              hipStream_t stream) {
    const float* z     = (const float*)d_in[0];
    const float* W_in  = (const float*)d_in[1];
    const float* b_in  = (const float*)d_in[2];
    const float* W_out = (const float*)d_in[3];
    const float* b_out = (const float*)d_in[4];
    const float* emb   = (const float*)d_in[5];
    const float* wp    = (const float*)d_in[6];
    const float* bp    = (const float*)d_in[7];
    const float* w1    = (const float*)d_in[8];
    const float* w2    = (const float*)d_in[9];
    const float* vs    = (const float*)d_in[10];
    const float* bs    = (const float*)d_in[11];

    char* p = (char*)d_ws;
    auto alloc = [&](size_t bytes) -> char* {
        char* r = p;
        p += (bytes + 255) & ~(size_t)255;
        return r;
    };
    float* h       = (float*)alloc((size_t)BB * NN * 64 * 4);          // 4.1 MB
    float* e1      = (float*)alloc((size_t)BB * NN * 4);
    float* e2      = (float*)alloc((size_t)BB * NN * 4);
    bf16*  A_bf    = (bf16*) alloc((size_t)NP * NP * 2);               // 8.4 MB
    bf16*  vs_bf   = (bf16*) alloc((size_t)NP * NP * 2);               // 8.4 MB
    bf16*  Tt_all  = (bf16*) alloc((size_t)BB * NP * NP * 2);          // 67 MB
    float* rsPart  = (float*)alloc((size_t)BB * 32 * NP * 4);          // 2.1 MB
    bf16*  hTcat   = (bf16*) alloc((size_t)512 * NP * 2);              // 2.1 MB
    float* AhPart  = (float*)alloc((size_t)4 * NP * 512 * 4);          // 16.8 MB
    bf16*  hsT     = (bf16*) alloc((size_t)BB * 128 * NP * 2);         // 4.2 MB
    float* xgPart  = (float*)alloc((size_t)NP * 8192 * 4);             // 67 MB ([n][by][z][j])
    bf16*  gbf     = (bf16*) alloc((size_t)BB * NN * 64 * 2);          // 2.0 MB
    bf16*  Wo_bf   = (bf16*) alloc((size_t)4096 * 64 * 2);             // 0.5 MB
    float* Wn_all  = (float*)alloc((size_t)NN * 8192 * 4);             // 65.5 MB

    k_h<<<BB * NN / 8, 256, 0, stream>>>(z, W_in, b_in, w1, w2, h, e1, e2);

    // mega: Tt(1024) | cvt_vs(16384) | A(2048) | wn(512) | hT(256) | wout(1024)
    k_mega<<<1024 + 16384 + 2048 + 512 + 256 + 1024, 256, 0, stream>>>(
        e1, e2, bs, Tt_all, vs, vs_bf, emb, A_bf, wp, Wn_all,
        h, hTcat, hsT, W_out, Wo_bf);

    // Ahcat[n][b*64+c] = sum_m A[n][m] h[b][m][c] -- K-split x4 (256 wg)
    k_gemm_bt<false, 4><<<dim3(16, 4, 4), 256, 0, stream>>>(
        A_bf, hTcat, AhPart, nullptr, NP, NP, NP, 512,
        0, 0, 0, (long long)NP * 512);
    k_redT<<<dim3(NP / 64, BB), 256, 0, stream>>>(AhPart, hsT);

    // fused {M = vs@T, P = exp(M), rowsums, xg partial = P@hs}, 8-phase,
    // XCD-locality swizzle (1-D grid)
    k_gemm256pv<<<512, 512, 0, stream>>>(
        vs_bf, Tt_all, hsT, xgPart, rsPart, NP, NP, NP,
        (long long)NP * NP, (long long)128 * NP);

    k_g<<<NN, 256, 0, stream>>>(Wn_all, bp, emb, xgPart, rsPart, gbf);
    // out[bn][o] = 0.1*tanh(g[bn] . W_out[o] + b_out[o]);  16000 = 125*128
    k_gemm_bt<true, 1><<<dim3(125, 32, 1), 256, 0, stream>>>(
        gbf, Wo_bf, (float*)d_out, b_out, 64, 64, 64, 4096, 0, 0, 0, 0);
}